// Round 1
// baseline (193.884 us; speedup 1.0000x reference)
//
#include <hip/hip_runtime.h>
#include <stdint.h>

#define Bc 2
#define Tc 2048
#define Cn 1024
#define Hc 16
#define CAc 64

typedef __attribute__((ext_vector_type(8))) short short8;
typedef __attribute__((ext_vector_type(4))) float f32x4;

// 0.125 (1/sqrt(64)) * log2(e): folded into q so attention uses raw v_exp_f32.
#define QSCALE 0.18033688011112042f

__device__ __forceinline__ unsigned short f2bf(float f) {
    unsigned int u = __builtin_bit_cast(unsigned int, f);
    return (unsigned short)((u + 0x7fffu + ((u >> 16) & 1u)) >> 16);
}
__device__ __forceinline__ unsigned int pack_rne(float a, float b) {
    return (unsigned int)f2bf(a) | ((unsigned int)f2bf(b) << 16);
}
// truncating bf16x2 pack in ONE v_perm_b32 (bias cancels in the P/sum ratio)
__device__ __forceinline__ unsigned int pack_trunc(float a, float b) {
    return __builtin_amdgcn_perm(__builtin_bit_cast(unsigned int, b),
                                 __builtin_bit_cast(unsigned int, a), 0x07060302u);
}

// async global->LDS, 16B per lane; HW scatters lane i to lds_base + i*16
__device__ __forceinline__ void async_cp16(const unsigned short* g, unsigned short* l) {
    __builtin_amdgcn_global_load_lds(
        (const __attribute__((address_space(1))) unsigned int*)g,
        (__attribute__((address_space(3))) unsigned int*)l,
        16, 0, 0);
}

// Self-detect input dtype from x. 1 -> bf16, 0 -> f32. Uniform across blocks.
__device__ __forceinline__ int detect_bf16(const unsigned short* x) {
    int c = 0;
#pragma unroll
    for (int i = 0; i < 64; i++) {
        unsigned short u = x[i * 2];           // even indices: f32 mantissa halves
        int e = (u >> 7) & 0xFF;
        c += (e >= 0x68 && e <= 0x90);
    }
    return c > 32;
}

__device__ __forceinline__ unsigned short ld_elem(const void* base, size_t off, int isbf) {
    return isbf ? ((const unsigned short*)base)[off] : f2bf(((const float*)base)[off]);
}

// ---------------------------------------------------------------------------
// prep: blocks [0,4096): convert x -> xb (skipped when x is bf16).
// [4096,7168): transpose w_q/w_k/w_v. [7168,8192): transpose w_o.
// ---------------------------------------------------------------------------
__global__ __launch_bounds__(256) void prep(
    const void* __restrict__ xin, unsigned short* __restrict__ xb,
    const void* __restrict__ wq, const void* __restrict__ wk,
    const void* __restrict__ wv, const void* __restrict__ wo,
    unsigned short* __restrict__ wT, unsigned short* __restrict__ woT)
{
    const int isbf = detect_bf16((const unsigned short*)xin);
    const int bx = blockIdx.x;
    if (bx < 4096) {
        if (isbf) return;
        int idx = (bx * 256 + threadIdx.x) * 4;
        const float* xf = (const float*)xin;
        float4 v = *(const float4*)(xf + idx);
        uint2 p;
        p.x = pack_rne(v.x, v.y);
        p.y = pack_rne(v.z, v.w);
        *(uint2*)(&xb[idx]) = p;
        return;
    }
    __shared__ unsigned short tile[32][33];
    const int t = threadIdx.x;
    const int tx = t & 31, ty = t >> 5;
    const void* src;
    unsigned short* dst;
    int R, Cw, r0, c0;
    if (bx < 7168) {
        int rem0 = bx - 4096;
        int g = rem0 >> 6;            // proj*16 + h
        int rem = rem0 & 63;
        int ct = rem >> 1;
        int at = rem & 1;
        int proj = g >> 4, h = g & 15;
        const void* wsel = (proj == 0) ? wq : ((proj == 1) ? wk : wv);
        src = isbf ? (const void*)((const unsigned short*)wsel + (size_t)h * Cn * CAc)
                   : (const void*)((const float*)wsel + (size_t)h * Cn * CAc);
        dst = wT + (size_t)g * CAc * Cn;
        R = Cn; Cw = CAc; r0 = ct * 32; c0 = at * 32;
    } else {
        int rem = bx - 7168;
        src = wo; dst = woT;
        R = Cn; Cw = Cn;
        r0 = (rem >> 5) * 32; c0 = (rem & 31) * 32;
    }
#pragma unroll
    for (int j = 0; j < 4; j++)
        tile[ty + j * 8][tx] = ld_elem(src, (size_t)(r0 + ty + j * 8) * Cw + c0 + tx, isbf);
    __syncthreads();
#pragma unroll
    for (int j = 0; j < 4; j++)
        dst[(size_t)(c0 + ty + j * 8) * R + r0 + tx] = tile[tx][ty + j * 8];
}

// ---------------------------------------------------------------------------
// QKV GEMM 128x128 block, TWO waves (128 threads), wave tile 64x128:
// LDS bytes/MAC drops 1.33x vs 64x64 wave tiles. K=1024, BK=32, async dbuf.
// q scaled by QSCALE. vT epilogue via LDS transpose (coalesced 16B stores).
// ---------------------------------------------------------------------------
__global__ __launch_bounds__(128, 2) void gemm_qkv(
    const void* __restrict__ xin,
    const unsigned short* __restrict__ xb,
    const unsigned short* __restrict__ Bt,
    unsigned short* __restrict__ o0,
    unsigned short* __restrict__ o1,
    unsigned short* __restrict__ o2)
{
    __shared__ alignas(16) unsigned short SH[4][128 * 32];   // Al=SH[0..1], Bl=SH[2..3]
    const int tid = threadIdx.x;
    const int wave = tid >> 6, lane = tid & 63;
    const int l15 = lane & 15, quad = lane >> 4;
    const int mBase = blockIdx.y * 128, nBase = blockIdx.x * 128;
    const int mOff = wave * 64;                   // wave tile: m 64, n 128

    const int isbf = detect_bf16((const unsigned short*)xin);
    const unsigned short* Amat = isbf ? (const unsigned short*)xin : xb;

    const int srow = lane >> 2;                   // 16 rows x 4 chunks per inst
    const int sgc  = (lane & 3) ^ (srow & 3);     // swizzled global chunk
    const int sw = (quad ^ (l15 & 3)) * 8;        // swizzled frag chunk

    f32x4 acc[4][8];
#pragma unroll
    for (int i = 0; i < 4; i++)
#pragma unroll
        for (int j = 0; j < 8; j++)
            acc[i][j] = (f32x4){0.f, 0.f, 0.f, 0.f};

    // stage K-step 0: wave stages its own 64 rows of A and of B (4 insts each)
#pragma unroll
    for (int t = 0; t < 4; t++) {
        int rl = wave * 64 + t * 16;
        async_cp16(Amat + (size_t)(mBase + rl + srow) * Cn + sgc * 8, &SH[0][rl * 32]);
        async_cp16(Bt   + (size_t)(nBase + rl + srow) * Cn + sgc * 8, &SH[2][rl * 32]);
    }
    __syncthreads();

    for (int kk = 0; kk < 32; kk++) {
        const int cur = kk & 1;
        if (kk < 31) {
            const int k1 = (kk + 1) * 32;
#pragma unroll
            for (int t = 0; t < 4; t++) {
                int rl = wave * 64 + t * 16;
                async_cp16(Amat + (size_t)(mBase + rl + srow) * Cn + k1 + sgc * 8, &SH[1 - cur][rl * 32]);
                async_cp16(Bt   + (size_t)(nBase + rl + srow) * Cn + k1 + sgc * 8, &SH[3 - cur][rl * 32]);
            }
        }
        short8 af[4], bfr[8];
#pragma unroll
        for (int i = 0; i < 4; i++)
            af[i] = *(const short8*)(&SH[cur][(mOff + i * 16 + l15) * 32 + sw]);
#pragma unroll
        for (int j = 0; j < 8; j++)
            bfr[j] = *(const short8*)(&SH[2 + cur][(j * 16 + l15) * 32 + sw]);
#pragma unroll
        for (int i = 0; i < 4; i++)
#pragma unroll
            for (int j = 0; j < 8; j++)
                acc[i][j] = __builtin_amdgcn_mfma_f32_16x16x32_bf16(af[i], bfr[j], acc[i][j], 0, 0, 0);
        __syncthreads();
    }

    const int bb = mBase >> 11;
    if (nBase < 2048) {
        const float sc = (nBase < 1024) ? QSCALE : 1.0f;
        unsigned short* dst = (nBase < 1024) ? o0 : o1;
#pragma unroll
        for (int i = 0; i < 4; i++) {
            int m0 = mBase + mOff + i * 16 + quad * 4;
            int t0 = m0 & (Tc - 1);
#pragma unroll
            for (int j = 0; j < 8; j++) {
                int n = nBase + j * 16 + l15;
                int h = (n >> 6) & 15, a = n & 63;
                size_t base = ((size_t)(bb * Hc + h) * Tc + t0) * CAc + a;
#pragma unroll
                for (int r = 0; r < 4; r++)
                    dst[base + (size_t)r * CAc] = f2bf(acc[i][j][r] * sc);
            }
        }
    } else {
        // v -> vT via LDS transpose (SH dead after K-loop; 32KB = 128x128)
        unsigned short* Cl = &SH[0][0];
#pragma unroll
        for (int i = 0; i < 4; i++) {
            int c16 = wave * 8 + i * 2 + (quad >> 1);      // 16B chunk of m (0..15)
            int p = quad & 1;                               // 8B half
#pragma unroll
            for (int j = 0; j < 8; j++) {
                int nl = j * 16 + l15;
                int cs = c16 ^ (nl & 7);
                uint2 v8;
                v8.x = pack_rne(acc[i][j][0], acc[i][j][1]);
                v8.y = pack_rne(acc[i][j][2], acc[i][j][3]);
                *(uint2*)(&Cl[nl * 128 + cs * 8 + p * 4]) = v8;
            }
        }
        __syncthreads();
        const int tLoc = mBase & (Tc - 1);                  // batch-local t base
#pragma unroll
        for (int pp = 0; pp < 16; pp++) {
            int vr = pp * 8 + wave * 4 + (lane >> 4);       // 0..127 (= n-local)
            int cc = lane & 15;                              // 16B chunk of t
            int cs = cc ^ (vr & 7);
            uint4 val = *(const uint4*)(&Cl[vr * 128 + cs * 8]);
            int n = nBase + vr;
            int hh = (n >> 6) & 15, a = n & 63;
            *(uint4*)(&o2[((size_t)(bb * Hc + hh) * CAc + a) * Tc + tLoc + cc * 8]) = val;
        }
    }
}

// ---------------------------------------------------------------------------
// Output GEMM: 64x128 tiles (512 blocks -> 2/CU), K=1024, BK=32, async dbuf.
// ---------------------------------------------------------------------------
__global__ __launch_bounds__(256) void gemm_out(
    const unsigned short* __restrict__ Amat,
    const unsigned short* __restrict__ Bt,
    void* __restrict__ o0,
    const void* __restrict__ xin)
{
    __shared__ alignas(16) unsigned short Al[2][64 * 32];
    __shared__ alignas(16) unsigned short Bl[2][128 * 32];
    const int tid = threadIdx.x;
    const int wave = tid >> 6, lane = tid & 63;
    const int l15 = lane & 15, quad = lane >> 4;
    const int mBase = blockIdx.y * 64, nBase = blockIdx.x * 128;
    const int mOff = (wave & 1) * 32, nOff = (wave >> 1) * 64;

    const int isbf = detect_bf16((const unsigned short*)xin);

    const int srow = lane >> 2;
    const int sgc  = (lane & 3) ^ (srow & 3);
    const int sw = (quad ^ (l15 & 3)) * 8;

    f32x4 acc[2][4];
#pragma unroll
    for (int i = 0; i < 2; i++)
#pragma unroll
        for (int j = 0; j < 4; j++)
            acc[i][j] = (f32x4){0.f, 0.f, 0.f, 0.f};

    {
        int rlA = wave * 16;
        async_cp16(Amat + (size_t)(mBase + rlA + srow) * Cn + sgc * 8, &Al[0][rlA * 32]);
#pragma unroll
        for (int t = 0; t < 2; t++) {
            int rlB = wave * 32 + t * 16;
            async_cp16(Bt + (size_t)(nBase + rlB + srow) * Cn + sgc * 8, &Bl[0][rlB * 32]);
        }
    }
    __syncthreads();

    for (int kk = 0; kk < 32; kk++) {
        const int cur = kk & 1;
        if (kk < 31) {
            const int k1 = (kk + 1) * 32;
            int rlA = wave * 16;
            async_cp16(Amat + (size_t)(mBase + rlA + srow) * Cn + k1 + sgc * 8, &Al[1 - cur][rlA * 32]);
#pragma unroll
            for (int t = 0; t < 2; t++) {
                int rlB = wave * 32 + t * 16;
                async_cp16(Bt + (size_t)(nBase + rlB + srow) * Cn + k1 + sgc * 8, &Bl[1 - cur][rlB * 32]);
            }
        }
        short8 af[2], bfr[4];
#pragma unroll
        for (int i = 0; i < 2; i++)
            af[i] = *(const short8*)(&Al[cur][(mOff + i * 16 + l15) * 32 + sw]);
#pragma unroll
        for (int j = 0; j < 4; j++)
            bfr[j] = *(const short8*)(&Bl[cur][(nOff + j * 16 + l15) * 32 + sw]);
#pragma unroll
        for (int i = 0; i < 2; i++)
#pragma unroll
            for (int j = 0; j < 4; j++)
                acc[i][j] = __builtin_amdgcn_mfma_f32_16x16x32_bf16(af[i], bfr[j], acc[i][j], 0, 0, 0);
        __syncthreads();
    }

#pragma unroll
    for (int i = 0; i < 2; i++) {
        int m0 = mBase + mOff + i * 16 + quad * 4;
#pragma unroll
        for (int j = 0; j < 4; j++) {
            int n = nBase + nOff + j * 16 + l15;
            if (isbf) {
#pragma unroll
                for (int r = 0; r < 4; r++)
                    ((unsigned short*)o0)[(size_t)(m0 + r) * Cn + n] = f2bf(acc[i][j][r]);
            } else {
#pragma unroll
                for (int r = 0; r < 4; r++)
                    ((float*)o0)[(size_t)(m0 + r) * Cn + n] = acc[i][j][r];
            }
        }
    }
}

// ---------------------------------------------------------------------------
// Flash attention, causal — k-slice ownership rewrite.
// One 64-row q-tile per block; 4 waves each OWN a 32-row k-slice of a 128-wide
// k-tile.  K/V go global->registers directly (L2-resident: 512KB per (b,h);
// XCD-affine bh swizzle keeps 4 heads per XCD L2).  NO K/V LDS staging, NO
// main-loop barriers.  Only LDS use in the loop: 4KB/wave swizzled P-exchange
// (quad transpose), bank-optimal (4-pass writes / 8-pass b128 reads).
// Waves accumulate partial O / rowsum over their k-subset (no-max softmax is a
// pure sum, so partials add); 3-barrier LDS tree reduces across waves once.
// Software pipeline: next-tile K issued after QK (K regs dead), next V after
// PV — single register set.  ~210 VGPR, __launch_bounds__(256,2).
// ---------------------------------------------------------------------------
__global__ __launch_bounds__(256, 2) void attn_t(
    const unsigned short* __restrict__ q,
    const unsigned short* __restrict__ k,
    const unsigned short* __restrict__ vT,
    unsigned short* __restrict__ y)
{
    // Per-wave 8320B region: P-exchange buffer (4KB) during the loop, then
    // O-partial dump [32 rows][65 f32] (pad 65 -> <=2-way bank aliasing).
    __shared__ alignas(16) float RW[4][32 * 65];    // 33280 B
    __shared__ float Rsum[4][64];                   // 1024 B
    const int bx = blockIdx.x;
    const int qt = 31 - (bx >> 5);                  // heavy tiles first
    const int bh = (bx & 7) * 4 + ((bx >> 3) & 3);  // XCD-affine: 4 bh per XCD slot
    const int h = bh & 15, b = bh >> 4;
    const int tid = threadIdx.x;
    const int wave = tid >> 6, lane = tid & 63;
    const int l15 = lane & 15, quad = lane >> 4;
    const size_t bhoff = (size_t)(b * Hc + h);
    const unsigned short* qh = q + bhoff * Tc * CAc;
    const unsigned short* kh = k + bhoff * Tc * CAc;
    const unsigned short* vh = vT + bhoff * CAc * Tc;

    // Q fragments, all 64 q-rows (B-operand): qf[qg*2+c]
    short8 qf[8];
#pragma unroll
    for (int qg = 0; qg < 4; qg++)
#pragma unroll
        for (int c = 0; c < 2; c++)
            qf[qg * 2 + c] = *(const short8*)(
                &qh[(size_t)(qt * 64 + qg * 16 + l15) * CAc + c * 32 + quad * 8]);

    f32x4 oacc[16], osum[4];
#pragma unroll
    for (int i = 0; i < 16; i++) oacc[i] = (f32x4){0.f, 0.f, 0.f, 0.f};
#pragma unroll
    for (int i = 0; i < 4; i++) osum[i] = (f32x4){0.f, 0.f, 0.f, 0.f};

    const unsigned short ONE = 0x3F80;
    short8 ones;
#pragma unroll
    for (int i = 0; i < 8; i++) ones[i] = (short)ONE;

    unsigned short* Pw = (unsigned short*)&RW[wave][0];
    const int hsw = l15 & 3;                        // P-exchange row swizzle

    // last k-tile index this wave participates in (floor divide, may be -1)
    const int qtmax = qt * 64 + 63;
    const int kb_last = (qtmax >= wave * 32) ? ((qtmax - wave * 32) >> 7) : -1;

    // per-lane base pointers for this wave's 32-row k-slice
    const unsigned short* kp  = kh + (size_t)(wave * 32 + l15) * CAc + quad * 8;
    const unsigned short* vp0 = vh + (size_t)l15 * Tc + wave * 32 + quad * 8;
    const unsigned short* vp1 = vp0 + (size_t)16 * Tc;
    const unsigned short* vp2 = vp0 + (size_t)32 * Tc;
    const unsigned short* vp3 = vp0 + (size_t)48 * Tc;

    short8 kf[4], vbf[4];
    if (kb_last >= 0) {
        // prologue: issue K then V for kb=0
        kf[0] = *(const short8*)(kp);
        kf[1] = *(const short8*)(kp + 32);
        kf[2] = *(const short8*)(kp + 16 * CAc);
        kf[3] = *(const short8*)(kp + 16 * CAc + 32);
        vbf[0] = *(const short8*)(vp0);
        vbf[1] = *(const short8*)(vp1);
        vbf[2] = *(const short8*)(vp2);
        vbf[3] = *(const short8*)(vp3);
    }

    for (int kb = 0; kb <= kb_last; ++kb) {
        const int k0w = kb * 128 + wave * 32;
        const int domask = (k0w + 32 > qt * 64);

        // ---- QK^T: zz[qg*2+s] = S^T tile (16 own-k rows x 16 q cols) ----
        f32x4 zz[8];
#pragma unroll
        for (int qg = 0; qg < 4; qg++)
#pragma unroll
            for (int s = 0; s < 2; s++) {
                f32x4 z = (f32x4){0.f, 0.f, 0.f, 0.f};
                z = __builtin_amdgcn_mfma_f32_16x16x32_bf16(kf[s * 2 + 0], qf[qg * 2 + 0], z, 0, 0, 0);
                z = __builtin_amdgcn_mfma_f32_16x16x32_bf16(kf[s * 2 + 1], qf[qg * 2 + 1], z, 0, 0, 0);
                zz[qg * 2 + s] = z;
            }

        // kf regs dead: prefetch next tile's K (hidden under exp/pack/PV)
        if (kb < kb_last) {
            kp += 128 * CAc;
            kf[0] = *(const short8*)(kp);
            kf[1] = *(const short8*)(kp + 32);
            kf[2] = *(const short8*)(kp + 16 * CAc);
            kf[3] = *(const short8*)(kp + 16 * CAc + 32);
        }

        // ---- exp2 + causal mask + truncating bf16 pack + P-exchange write ----
#pragma unroll
        for (int qg = 0; qg < 4; qg++) {
            const int tg = qt * 64 + qg * 16 + l15;
#pragma unroll
            for (int s = 0; s < 2; s++) {
                float sv[4];
#pragma unroll
                for (int r = 0; r < 4; r++) {
                    float e = __builtin_amdgcn_exp2f(zz[qg * 2 + s][r]);
                    if (domask) {
                        int sg = k0w + s * 16 + quad * 4 + r;
                        e = (sg <= tg) ? e : 0.f;
                    }
                    sv[r] = e;
                }
                uint2 pv;
                pv.x = pack_trunc(sv[0], sv[1]);
                pv.y = pack_trunc(sv[2], sv[3]);
                // row = q (qg*16+l15); 16B chunk (s*2+(quad>>1)) ^ hsw; 8B half quad&1
                *(uint2*)(&Pw[(qg * 16 + l15) * 32 +
                              (((s * 2 + (quad >> 1)) ^ hsw) * 8) + (quad & 1) * 4]) = pv;
            }
        }

        // ---- PV + rowsum (per-wave LDS round-trip; same-wave lgkmcnt only) ----
#pragma unroll
        for (int qg = 0; qg < 4; qg++) {
            short8 pa = *(const short8*)(&Pw[(qg * 16 + l15) * 32 + ((quad ^ hsw) * 8)]);
#pragma unroll
            for (int cag = 0; cag < 4; cag++)
                oacc[qg * 4 + cag] = __builtin_amdgcn_mfma_f32_16x16x32_bf16(pa, vbf[cag], oacc[qg * 4 + cag], 0, 0, 0);
            osum[qg] = __builtin_amdgcn_mfma_f32_16x16x32_bf16(pa, ones, osum[qg], 0, 0, 0);
        }

        // vbf regs dead: prefetch next tile's V (hidden under next QK/exp)
        if (kb < kb_last) {
            vp0 += 128; vp1 += 128; vp2 += 128; vp3 += 128;
            vbf[0] = *(const short8*)(vp0);
            vbf[1] = *(const short8*)(vp1);
            vbf[2] = *(const short8*)(vp2);
            vbf[3] = *(const short8*)(vp3);
        }
    }

    // ---- cross-wave reduction of partial O / rowsum (2 half-dumps) ----
    // dump A: rows 0..31 (qg 0,1) into own region (clobbers own P buffer: safe)
#pragma unroll
    for (int qg = 0; qg < 2; qg++)
#pragma unroll
        for (int cag = 0; cag < 4; cag++)
#pragma unroll
            for (int r = 0; r < 4; r++)
                RW[wave][(qg * 16 + quad * 4 + r) * 65 + cag * 16 + l15] = oacc[qg * 4 + cag][r];
    if (l15 == 0)
#pragma unroll
        for (int qg = 0; qg < 4; qg++)
#pragma unroll
            for (int r = 0; r < 4; r++)
                Rsum[wave][qg * 16 + quad * 4 + r] = osum[qg][r];
    __syncthreads();

    float fo[16];
#pragma unroll
    for (int i = 0; i < 16; i++) fo[i] = 0.f;
    if (wave < 2) {
#pragma unroll
        for (int v = 0; v < 4; v++)
#pragma unroll
            for (int cag = 0; cag < 4; cag++)
#pragma unroll
                for (int r = 0; r < 4; r++)
                    fo[cag * 4 + r] += RW[v][(wave * 16 + quad * 4 + r) * 65 + cag * 16 + l15];
    }
    __syncthreads();

    // dump B: rows 32..63 (qg 2,3)
#pragma unroll
    for (int qg = 2; qg < 4; qg++)
#pragma unroll
        for (int cag = 0; cag < 4; cag++)
#pragma unroll
            for (int r = 0; r < 4; r++)
                RW[wave][((qg - 2) * 16 + quad * 4 + r) * 65 + cag * 16 + l15] = oacc[qg * 4 + cag][r];
    __syncthreads();

    if (wave >= 2) {
#pragma unroll
        for (int v = 0; v < 4; v++)
#pragma unroll
            for (int cag = 0; cag < 4; cag++)
#pragma unroll
                for (int r = 0; r < 4; r++)
                    fo[cag * 4 + r] += RW[v][((wave - 2) * 16 + quad * 4 + r) * 65 + cag * 16 + l15];
    }

    float fs[4];
#pragma unroll
    for (int r = 0; r < 4; r++) {
        float s = 0.f;
#pragma unroll
        for (int v = 0; v < 4; v++)
            s += Rsum[v][wave * 16 + quad * 4 + r];
        fs[r] = s;
    }
    float ri[4];
#pragma unroll
    for (int r = 0; r < 4; r++) ri[r] = 1.0f / fs[r];

#pragma unroll
    for (int cag = 0; cag < 4; cag++)
#pragma unroll
        for (int r = 0; r < 4; r++) {
            int t = qt * 64 + wave * 16 + quad * 4 + r;
            y[((size_t)b * Tc + t) * Cn + h * CAc + cag * 16 + l15] = f2bf(fo[cag * 4 + r] * ri[r]);
        }
}

// ---------------------------------------------------------------------------
extern "C" void kernel_launch(void* const* d_in, const int* in_sizes, int n_in,
                              void* d_out, int out_size, void* d_ws, size_t ws_size,
                              hipStream_t stream) {
    const void* x  = d_in[0];
    const void* wq = d_in[1];
    const void* wk = d_in[2];
    const void* wv = d_in[3];
    const void* wo = d_in[4];
    char* ws = (char*)d_ws;
    // ws layout (MB): wT@1(6) | woT@7(2) | xb@9(8) | q@17(8) | k@25(8) | vT@33(8) | y@41(8)
    unsigned short* wT  = (unsigned short*)(ws + ((size_t)1 << 20));
    unsigned short* woT = (unsigned short*)(ws + ((size_t)7 << 20));
    unsigned short* xb  = (unsigned short*)(ws + ((size_t)9 << 20));
    unsigned short* qb  = (unsigned short*)(ws + ((size_t)17 << 20));
    unsigned short* kb  = (unsigned short*)(ws + ((size_t)25 << 20));
    unsigned short* vTb = (unsigned short*)(ws + ((size_t)33 << 20));
    unsigned short* yb  = (unsigned short*)(ws + ((size_t)41 << 20));

    prep<<<dim3(8192), dim3(256), 0, stream>>>(x, xb, wq, wk, wv, wo, wT, woT);
    gemm_qkv<<<dim3(24, 32), dim3(128), 0, stream>>>(x, xb, wT, qb, kb, vTb);
    attn_t<<<dim3(1024), dim3(256), 0, stream>>>(qb, kb, vTb, yb);
    gemm_out<<<dim3(8, 64), dim3(256), 0, stream>>>(yb, woT, d_out, x);
}

// Round 3
// 190.989 us; speedup vs baseline: 1.0152x; 1.0152x over previous
//
#include <hip/hip_runtime.h>
#include <stdint.h>

#define Bc 2
#define Tc 2048
#define Cn 1024
#define Hc 16
#define CAc 64

typedef __attribute__((ext_vector_type(8))) short short8;
typedef __attribute__((ext_vector_type(4))) float f32x4;

// 0.125 (1/sqrt(64)) * log2(e): folded into q so attention uses raw v_exp_f32.
#define QSCALE 0.18033688011112042f

__device__ __forceinline__ unsigned short f2bf(float f) {
    unsigned int u = __builtin_bit_cast(unsigned int, f);
    return (unsigned short)((u + 0x7fffu + ((u >> 16) & 1u)) >> 16);
}
__device__ __forceinline__ unsigned int pack_rne(float a, float b) {
    return (unsigned int)f2bf(a) | ((unsigned int)f2bf(b) << 16);
}
// truncating bf16x2 pack in ONE v_perm_b32 (bias cancels in the P/sum ratio)
__device__ __forceinline__ unsigned int pack_trunc(float a, float b) {
    return __builtin_amdgcn_perm(__builtin_bit_cast(unsigned int, b),
                                 __builtin_bit_cast(unsigned int, a), 0x07060302u);
}

// async global->LDS, 16B per lane; HW scatters lane i to lds_base + i*16
__device__ __forceinline__ void async_cp16(const unsigned short* g, unsigned short* l) {
    __builtin_amdgcn_global_load_lds(
        (const __attribute__((address_space(1))) unsigned int*)g,
        (__attribute__((address_space(3))) unsigned int*)l,
        16, 0, 0);
}

// Self-detect input dtype from x. 1 -> bf16, 0 -> f32. Uniform across blocks.
__device__ __forceinline__ int detect_bf16(const unsigned short* x) {
    int c = 0;
#pragma unroll
    for (int i = 0; i < 64; i++) {
        unsigned short u = x[i * 2];           // even indices: f32 mantissa halves
        int e = (u >> 7) & 0xFF;
        c += (e >= 0x68 && e <= 0x90);
    }
    return c > 32;
}

__device__ __forceinline__ unsigned short ld_elem(const void* base, size_t off, int isbf) {
    return isbf ? ((const unsigned short*)base)[off] : f2bf(((const float*)base)[off]);
}

// ---------------------------------------------------------------------------
// prep: blocks [0,4096): convert x -> xb (skipped when x is bf16).
// [4096,7168): transpose w_q/w_k/w_v. [7168,8192): transpose w_o.
// ---------------------------------------------------------------------------
__global__ __launch_bounds__(256) void prep(
    const void* __restrict__ xin, unsigned short* __restrict__ xb,
    const void* __restrict__ wq, const void* __restrict__ wk,
    const void* __restrict__ wv, const void* __restrict__ wo,
    unsigned short* __restrict__ wT, unsigned short* __restrict__ woT)
{
    const int isbf = detect_bf16((const unsigned short*)xin);
    const int bx = blockIdx.x;
    if (bx < 4096) {
        if (isbf) return;
        int idx = (bx * 256 + threadIdx.x) * 4;
        const float* xf = (const float*)xin;
        float4 v = *(const float4*)(xf + idx);
        uint2 p;
        p.x = pack_rne(v.x, v.y);
        p.y = pack_rne(v.z, v.w);
        *(uint2*)(&xb[idx]) = p;
        return;
    }
    __shared__ unsigned short tile[32][33];
    const int t = threadIdx.x;
    const int tx = t & 31, ty = t >> 5;
    const void* src;
    unsigned short* dst;
    int R, Cw, r0, c0;
    if (bx < 7168) {
        int rem0 = bx - 4096;
        int g = rem0 >> 6;            // proj*16 + h
        int rem = rem0 & 63;
        int ct = rem >> 1;
        int at = rem & 1;
        int proj = g >> 4, h = g & 15;
        const void* wsel = (proj == 0) ? wq : ((proj == 1) ? wk : wv);
        src = isbf ? (const void*)((const unsigned short*)wsel + (size_t)h * Cn * CAc)
                   : (const void*)((const float*)wsel + (size_t)h * Cn * CAc);
        dst = wT + (size_t)g * CAc * Cn;
        R = Cn; Cw = CAc; r0 = ct * 32; c0 = at * 32;
    } else {
        int rem = bx - 7168;
        src = wo; dst = woT;
        R = Cn; Cw = Cn;
        r0 = (rem >> 5) * 32; c0 = (rem & 31) * 32;
    }
#pragma unroll
    for (int j = 0; j < 4; j++)
        tile[ty + j * 8][tx] = ld_elem(src, (size_t)(r0 + ty + j * 8) * Cw + c0 + tx, isbf);
    __syncthreads();
#pragma unroll
    for (int j = 0; j < 4; j++)
        dst[(size_t)(c0 + ty + j * 8) * R + r0 + tx] = tile[tx][ty + j * 8];
}

// ---------------------------------------------------------------------------
// QKV GEMM 128x128 block, TWO waves (128 threads), wave tile 64x128:
// LDS bytes/MAC drops 1.33x vs 64x64 wave tiles. K=1024, BK=32, async dbuf.
// q scaled by QSCALE. vT epilogue via LDS transpose (coalesced 16B stores).
// ---------------------------------------------------------------------------
__global__ __launch_bounds__(128, 2) void gemm_qkv(
    const void* __restrict__ xin,
    const unsigned short* __restrict__ xb,
    const unsigned short* __restrict__ Bt,
    unsigned short* __restrict__ o0,
    unsigned short* __restrict__ o1,
    unsigned short* __restrict__ o2)
{
    __shared__ alignas(16) unsigned short SH[4][128 * 32];   // Al=SH[0..1], Bl=SH[2..3]
    const int tid = threadIdx.x;
    const int wave = tid >> 6, lane = tid & 63;
    const int l15 = lane & 15, quad = lane >> 4;
    const int mBase = blockIdx.y * 128, nBase = blockIdx.x * 128;
    const int mOff = wave * 64;                   // wave tile: m 64, n 128

    const int isbf = detect_bf16((const unsigned short*)xin);
    const unsigned short* Amat = isbf ? (const unsigned short*)xin : xb;

    const int srow = lane >> 2;                   // 16 rows x 4 chunks per inst
    const int sgc  = (lane & 3) ^ (srow & 3);     // swizzled global chunk
    const int sw = (quad ^ (l15 & 3)) * 8;        // swizzled frag chunk

    f32x4 acc[4][8];
#pragma unroll
    for (int i = 0; i < 4; i++)
#pragma unroll
        for (int j = 0; j < 8; j++)
            acc[i][j] = (f32x4){0.f, 0.f, 0.f, 0.f};

    // stage K-step 0: wave stages its own 64 rows of A and of B (4 insts each)
#pragma unroll
    for (int t = 0; t < 4; t++) {
        int rl = wave * 64 + t * 16;
        async_cp16(Amat + (size_t)(mBase + rl + srow) * Cn + sgc * 8, &SH[0][rl * 32]);
        async_cp16(Bt   + (size_t)(nBase + rl + srow) * Cn + sgc * 8, &SH[2][rl * 32]);
    }
    __syncthreads();

    for (int kk = 0; kk < 32; kk++) {
        const int cur = kk & 1;
        if (kk < 31) {
            const int k1 = (kk + 1) * 32;
#pragma unroll
            for (int t = 0; t < 4; t++) {
                int rl = wave * 64 + t * 16;
                async_cp16(Amat + (size_t)(mBase + rl + srow) * Cn + k1 + sgc * 8, &SH[1 - cur][rl * 32]);
                async_cp16(Bt   + (size_t)(nBase + rl + srow) * Cn + k1 + sgc * 8, &SH[3 - cur][rl * 32]);
            }
        }
        short8 af[4], bfr[8];
#pragma unroll
        for (int i = 0; i < 4; i++)
            af[i] = *(const short8*)(&SH[cur][(mOff + i * 16 + l15) * 32 + sw]);
#pragma unroll
        for (int j = 0; j < 8; j++)
            bfr[j] = *(const short8*)(&SH[2 + cur][(j * 16 + l15) * 32 + sw]);
#pragma unroll
        for (int i = 0; i < 4; i++)
#pragma unroll
            for (int j = 0; j < 8; j++)
                acc[i][j] = __builtin_amdgcn_mfma_f32_16x16x32_bf16(af[i], bfr[j], acc[i][j], 0, 0, 0);
        __syncthreads();
    }

    const int bb = mBase >> 11;
    if (nBase < 2048) {
        const float sc = (nBase < 1024) ? QSCALE : 1.0f;
        unsigned short* dst = (nBase < 1024) ? o0 : o1;
#pragma unroll
        for (int i = 0; i < 4; i++) {
            int m0 = mBase + mOff + i * 16 + quad * 4;
            int t0 = m0 & (Tc - 1);
#pragma unroll
            for (int j = 0; j < 8; j++) {
                int n = nBase + j * 16 + l15;
                int h = (n >> 6) & 15, a = n & 63;
                size_t base = ((size_t)(bb * Hc + h) * Tc + t0) * CAc + a;
#pragma unroll
                for (int r = 0; r < 4; r++)
                    dst[base + (size_t)r * CAc] = f2bf(acc[i][j][r] * sc);
            }
        }
    } else {
        // v -> vT via LDS transpose (SH dead after K-loop; 32KB = 128x128)
        unsigned short* Cl = &SH[0][0];
#pragma unroll
        for (int i = 0; i < 4; i++) {
            int c16 = wave * 8 + i * 2 + (quad >> 1);      // 16B chunk of m (0..15)
            int p = quad & 1;                               // 8B half
#pragma unroll
            for (int j = 0; j < 8; j++) {
                int nl = j * 16 + l15;
                int cs = c16 ^ (nl & 7);
                uint2 v8;
                v8.x = pack_rne(acc[i][j][0], acc[i][j][1]);
                v8.y = pack_rne(acc[i][j][2], acc[i][j][3]);
                *(uint2*)(&Cl[nl * 128 + cs * 8 + p * 4]) = v8;
            }
        }
        __syncthreads();
        const int tLoc = mBase & (Tc - 1);                  // batch-local t base
#pragma unroll
        for (int pp = 0; pp < 16; pp++) {
            int vr = pp * 8 + wave * 4 + (lane >> 4);       // 0..127 (= n-local)
            int cc = lane & 15;                              // 16B chunk of t
            int cs = cc ^ (vr & 7);
            uint4 val = *(const uint4*)(&Cl[vr * 128 + cs * 8]);
            int n = nBase + vr;
            int hh = (n >> 6) & 15, a = n & 63;
            *(uint4*)(&o2[((size_t)(bb * Hc + hh) * CAc + a) * Tc + tLoc + cc * 8]) = val;
        }
    }
}

// ---------------------------------------------------------------------------
// Output GEMM: 64x128 tiles (512 blocks -> 2/CU), K=1024, BK=32, async dbuf.
// ---------------------------------------------------------------------------
__global__ __launch_bounds__(256) void gemm_out(
    const unsigned short* __restrict__ Amat,
    const unsigned short* __restrict__ Bt,
    void* __restrict__ o0,
    const void* __restrict__ xin)
{
    __shared__ alignas(16) unsigned short Al[2][64 * 32];
    __shared__ alignas(16) unsigned short Bl[2][128 * 32];
    const int tid = threadIdx.x;
    const int wave = tid >> 6, lane = tid & 63;
    const int l15 = lane & 15, quad = lane >> 4;
    const int mBase = blockIdx.y * 64, nBase = blockIdx.x * 128;
    const int mOff = (wave & 1) * 32, nOff = (wave >> 1) * 64;

    const int isbf = detect_bf16((const unsigned short*)xin);

    const int srow = lane >> 2;
    const int sgc  = (lane & 3) ^ (srow & 3);
    const int sw = (quad ^ (l15 & 3)) * 8;

    f32x4 acc[2][4];
#pragma unroll
    for (int i = 0; i < 2; i++)
#pragma unroll
        for (int j = 0; j < 4; j++)
            acc[i][j] = (f32x4){0.f, 0.f, 0.f, 0.f};

    {
        int rlA = wave * 16;
        async_cp16(Amat + (size_t)(mBase + rlA + srow) * Cn + sgc * 8, &Al[0][rlA * 32]);
#pragma unroll
        for (int t = 0; t < 2; t++) {
            int rlB = wave * 32 + t * 16;
            async_cp16(Bt + (size_t)(nBase + rlB + srow) * Cn + sgc * 8, &Bl[0][rlB * 32]);
        }
    }
    __syncthreads();

    for (int kk = 0; kk < 32; kk++) {
        const int cur = kk & 1;
        if (kk < 31) {
            const int k1 = (kk + 1) * 32;
            int rlA = wave * 16;
            async_cp16(Amat + (size_t)(mBase + rlA + srow) * Cn + k1 + sgc * 8, &Al[1 - cur][rlA * 32]);
#pragma unroll
            for (int t = 0; t < 2; t++) {
                int rlB = wave * 32 + t * 16;
                async_cp16(Bt + (size_t)(nBase + rlB + srow) * Cn + k1 + sgc * 8, &Bl[1 - cur][rlB * 32]);
            }
        }
        short8 af[2], bfr[4];
#pragma unroll
        for (int i = 0; i < 2; i++)
            af[i] = *(const short8*)(&Al[cur][(mOff + i * 16 + l15) * 32 + sw]);
#pragma unroll
        for (int j = 0; j < 4; j++)
            bfr[j] = *(const short8*)(&Bl[cur][(nOff + j * 16 + l15) * 32 + sw]);
#pragma unroll
        for (int i = 0; i < 2; i++)
#pragma unroll
            for (int j = 0; j < 4; j++)
                acc[i][j] = __builtin_amdgcn_mfma_f32_16x16x32_bf16(af[i], bfr[j], acc[i][j], 0, 0, 0);
        __syncthreads();
    }

#pragma unroll
    for (int i = 0; i < 2; i++) {
        int m0 = mBase + mOff + i * 16 + quad * 4;
#pragma unroll
        for (int j = 0; j < 4; j++) {
            int n = nBase + nOff + j * 16 + l15;
            if (isbf) {
#pragma unroll
                for (int r = 0; r < 4; r++)
                    ((unsigned short*)o0)[(size_t)(m0 + r) * Cn + n] = f2bf(acc[i][j][r]);
            } else {
#pragma unroll
                for (int r = 0; r < 4; r++)
                    ((float*)o0)[(size_t)(m0 + r) * Cn + n] = acc[i][j][r];
            }
        }
    }
}

// ---------------------------------------------------------------------------
// Flash attention, causal — k-slice ownership + BALANCED Q-TILE PAIRING.
// 512 blocks = 32 bh x 16 pairs.  Each block processes q-tile (31-p) then
// q-tile p SEQUENTIALLY: work = 33 k-tile-units for EVERY block, so the
// 2-blocks/CU residency (8 waves/CU) stays flat start-to-finish with no
// assumption about the undefined block->CU mapping (fixes R0's 17% occupancy
// tail: CU work spreads of 52..80 units -> exactly 66 everywhere).
// Inner loop unchanged: 4 waves own 32-row k-slices of a 128-wide k-tile,
// K/V global->reg (L2-resident, XCD-affine bh), no main-loop barriers,
// per-wave 4KB swizzled P-exchange, partial-O cross-wave tree at tile end.
// One extra __syncthreads() between the two tiles guards the shared RW buf.
// ---------------------------------------------------------------------------
__global__ __launch_bounds__(256, 2) void attn_t(
    const unsigned short* __restrict__ q,
    const unsigned short* __restrict__ k,
    const unsigned short* __restrict__ vT,
    unsigned short* __restrict__ y)
{
    // Per-wave 8320B region: P-exchange buffer (4KB) during the loop, then
    // O-partial dump [32 rows][65 f32] (pad 65 -> <=2-way bank aliasing).
    __shared__ alignas(16) float RW[4][32 * 65];    // 33280 B
    __shared__ float Rsum[4][64];                   // 1024 B
    const int bx = blockIdx.x;
    const int pr = bx >> 5;                         // pair index 0..15
    const int bh = (bx & 7) * 4 + ((bx >> 3) & 3);  // XCD-affine: 4 bh per XCD slot
    const int h = bh & 15, b = bh >> 4;
    const int tid = threadIdx.x;
    const int wave = tid >> 6, lane = tid & 63;
    const int l15 = lane & 15, quad = lane >> 4;
    const size_t bhoff = (size_t)(b * Hc + h);
    const unsigned short* qh = q + bhoff * Tc * CAc;
    const unsigned short* kh = k + bhoff * Tc * CAc;
    const unsigned short* vh = vT + bhoff * CAc * Tc;

    const unsigned short ONE = 0x3F80;
    short8 ones;
#pragma unroll
    for (int i = 0; i < 8; i++) ones[i] = (short)ONE;

    unsigned short* Pw = (unsigned short*)&RW[wave][0];
    const int hsw = l15 & 3;                        // P-exchange row swizzle

    for (int half = 0; half < 2; half++) {
        const int qt = half ? pr : (31 - pr);       // heavy tile first

        // Q fragments, all 64 q-rows (B-operand): qf[qg*2+c]
        short8 qf[8];
#pragma unroll
        for (int qg = 0; qg < 4; qg++)
#pragma unroll
            for (int c = 0; c < 2; c++)
                qf[qg * 2 + c] = *(const short8*)(
                    &qh[(size_t)(qt * 64 + qg * 16 + l15) * CAc + c * 32 + quad * 8]);

        f32x4 oacc[16], osum[4];
#pragma unroll
        for (int i = 0; i < 16; i++) oacc[i] = (f32x4){0.f, 0.f, 0.f, 0.f};
#pragma unroll
        for (int i = 0; i < 4; i++) osum[i] = (f32x4){0.f, 0.f, 0.f, 0.f};

        // last k-tile index this wave participates in (floor divide, may be -1)
        const int qtmax = qt * 64 + 63;
        const int kb_last = (qtmax >= wave * 32) ? ((qtmax - wave * 32) >> 7) : -1;

        // per-lane base pointers for this wave's 32-row k-slice
        const unsigned short* kp  = kh + (size_t)(wave * 32 + l15) * CAc + quad * 8;
        const unsigned short* vp0 = vh + (size_t)l15 * Tc + wave * 32 + quad * 8;
        const unsigned short* vp1 = vp0 + (size_t)16 * Tc;
        const unsigned short* vp2 = vp0 + (size_t)32 * Tc;
        const unsigned short* vp3 = vp0 + (size_t)48 * Tc;

        short8 kf[4], vbf[4];
        if (kb_last >= 0) {
            kf[0] = *(const short8*)(kp);
            kf[1] = *(const short8*)(kp + 32);
            kf[2] = *(const short8*)(kp + 16 * CAc);
            kf[3] = *(const short8*)(kp + 16 * CAc + 32);
            vbf[0] = *(const short8*)(vp0);
            vbf[1] = *(const short8*)(vp1);
            vbf[2] = *(const short8*)(vp2);
            vbf[3] = *(const short8*)(vp3);
        }

        for (int kb = 0; kb <= kb_last; ++kb) {
            const int k0w = kb * 128 + wave * 32;
            const int domask = (k0w + 32 > qt * 64);

            // ---- QK^T: zz[qg*2+s] = S^T tile (16 own-k rows x 16 q cols) ----
            f32x4 zz[8];
#pragma unroll
            for (int qg = 0; qg < 4; qg++)
#pragma unroll
                for (int s = 0; s < 2; s++) {
                    f32x4 z = (f32x4){0.f, 0.f, 0.f, 0.f};
                    z = __builtin_amdgcn_mfma_f32_16x16x32_bf16(kf[s * 2 + 0], qf[qg * 2 + 0], z, 0, 0, 0);
                    z = __builtin_amdgcn_mfma_f32_16x16x32_bf16(kf[s * 2 + 1], qf[qg * 2 + 1], z, 0, 0, 0);
                    zz[qg * 2 + s] = z;
                }

            // kf regs dead: prefetch next tile's K (hidden under exp/pack/PV)
            if (kb < kb_last) {
                kp += 128 * CAc;
                kf[0] = *(const short8*)(kp);
                kf[1] = *(const short8*)(kp + 32);
                kf[2] = *(const short8*)(kp + 16 * CAc);
                kf[3] = *(const short8*)(kp + 16 * CAc + 32);
            }

            // ---- exp2 + causal mask + truncating bf16 pack + P-exchange write ----
#pragma unroll
            for (int qg = 0; qg < 4; qg++) {
                const int tg = qt * 64 + qg * 16 + l15;
#pragma unroll
                for (int s = 0; s < 2; s++) {
                    float sv[4];
#pragma unroll
                    for (int r = 0; r < 4; r++) {
                        float e = __builtin_amdgcn_exp2f(zz[qg * 2 + s][r]);
                        if (domask) {
                            int sg = k0w + s * 16 + quad * 4 + r;
                            e = (sg <= tg) ? e : 0.f;
                        }
                        sv[r] = e;
                    }
                    uint2 pv;
                    pv.x = pack_trunc(sv[0], sv[1]);
                    pv.y = pack_trunc(sv[2], sv[3]);
                    *(uint2*)(&Pw[(qg * 16 + l15) * 32 +
                                  (((s * 2 + (quad >> 1)) ^ hsw) * 8) + (quad & 1) * 4]) = pv;
                }
            }

            // ---- PV + rowsum (per-wave LDS round-trip; same-wave lgkmcnt only) ----
#pragma unroll
            for (int qg = 0; qg < 4; qg++) {
                short8 pa = *(const short8*)(&Pw[(qg * 16 + l15) * 32 + ((quad ^ hsw) * 8)]);
#pragma unroll
                for (int cag = 0; cag < 4; cag++)
                    oacc[qg * 4 + cag] = __builtin_amdgcn_mfma_f32_16x16x32_bf16(pa, vbf[cag], oacc[qg * 4 + cag], 0, 0, 0);
                osum[qg] = __builtin_amdgcn_mfma_f32_16x16x32_bf16(pa, ones, osum[qg], 0, 0, 0);
            }

            // vbf regs dead: prefetch next tile's V (hidden under next QK/exp)
            if (kb < kb_last) {
                vp0 += 128; vp1 += 128; vp2 += 128; vp3 += 128;
                vbf[0] = *(const short8*)(vp0);
                vbf[1] = *(const short8*)(vp1);
                vbf[2] = *(const short8*)(vp2);
                vbf[3] = *(const short8*)(vp3);
            }
        }

        // ---- cross-wave reduction of partial O / rowsum (2 half-dumps) ----
#pragma unroll
        for (int qg = 0; qg < 2; qg++)
#pragma unroll
            for (int cag = 0; cag < 4; cag++)
#pragma unroll
                for (int r = 0; r < 4; r++)
                    RW[wave][(qg * 16 + quad * 4 + r) * 65 + cag * 16 + l15] = oacc[qg * 4 + cag][r];
        if (l15 == 0)
#pragma unroll
            for (int qg = 0; qg < 4; qg++)
#pragma unroll
                for (int r = 0; r < 4; r++)
                    Rsum[wave][qg * 16 + quad * 4 + r] = osum[qg][r];
        __syncthreads();

        float fo[16];
#pragma unroll
        for (int i = 0; i < 16; i++) fo[i] = 0.f;
        if (wave < 2) {
#pragma unroll
            for (int v = 0; v < 4; v++)
#pragma unroll
                for (int cag = 0; cag < 4; cag++)
#pragma unroll
                    for (int r = 0; r < 4; r++)
                        fo[cag * 4 + r] += RW[v][(wave * 16 + quad * 4 + r) * 65 + cag * 16 + l15];
        }
        __syncthreads();

        // dump B: rows 32..63 (qg 2,3)
#pragma unroll
        for (int qg = 2; qg < 4; qg++)
#pragma unroll
            for (int cag = 0; cag < 4; cag++)
#pragma unroll
                for (int r = 0; r < 4; r++)
                    RW[wave][((qg - 2) * 16 + quad * 4 + r) * 65 + cag * 16 + l15] = oacc[qg * 4 + cag][r];
        __syncthreads();

        if (wave >= 2) {
#pragma unroll
            for (int v = 0; v < 4; v++)
#pragma unroll
                for (int cag = 0; cag < 4; cag++)
#pragma unroll
                    for (int r = 0; r < 4; r++)
                        fo[cag * 4 + r] += RW[v][((wave - 2) * 16 + quad * 4 + r) * 65 + cag * 16 + l15];
        }

        float fs[4];
#pragma unroll
        for (int r = 0; r < 4; r++) {
            float s = 0.f;
#pragma unroll
            for (int v = 0; v < 4; v++)
                s += Rsum[v][wave * 16 + quad * 4 + r];
            fs[r] = s;
        }
        float ri[4];
#pragma unroll
        for (int r = 0; r < 4; r++) ri[r] = 1.0f / fs[r];

#pragma unroll
        for (int cag = 0; cag < 4; cag++)
#pragma unroll
            for (int r = 0; r < 4; r++) {
                int t = qt * 64 + wave * 16 + quad * 4 + r;
                y[((size_t)b * Tc + t) * Cn + h * CAc + cag * 16 + l15] = f2bf(fo[cag * 4 + r] * ri[r]);
            }

        // guard RW/Rsum reuse before the second tile starts writing them
        if (half == 0) __syncthreads();
    }
}

// ---------------------------------------------------------------------------
extern "C" void kernel_launch(void* const* d_in, const int* in_sizes, int n_in,
                              void* d_out, int out_size, void* d_ws, size_t ws_size,
                              hipStream_t stream) {
    const void* x  = d_in[0];
    const void* wq = d_in[1];
    const void* wk = d_in[2];
    const void* wv = d_in[3];
    const void* wo = d_in[4];
    char* ws = (char*)d_ws;
    // ws layout (MB): wT@1(6) | woT@7(2) | xb@9(8) | q@17(8) | k@25(8) | vT@33(8) | y@41(8)
    unsigned short* wT  = (unsigned short*)(ws + ((size_t)1 << 20));
    unsigned short* woT = (unsigned short*)(ws + ((size_t)7 << 20));
    unsigned short* xb  = (unsigned short*)(ws + ((size_t)9 << 20));
    unsigned short* qb  = (unsigned short*)(ws + ((size_t)17 << 20));
    unsigned short* kb  = (unsigned short*)(ws + ((size_t)25 << 20));
    unsigned short* vTb = (unsigned short*)(ws + ((size_t)33 << 20));
    unsigned short* yb  = (unsigned short*)(ws + ((size_t)41 << 20));

    prep<<<dim3(8192), dim3(256), 0, stream>>>(x, xb, wq, wk, wv, wo, wT, woT);
    gemm_qkv<<<dim3(24, 32), dim3(128), 0, stream>>>(x, xb, wT, qb, kb, vTb);
    attn_t<<<dim3(512), dim3(256), 0, stream>>>(qb, kb, vTb, yb);
    gemm_out<<<dim3(8, 64), dim3(256), 0, stream>>>(yb, woT, d_out, x);
}

// Round 4
// 186.523 us; speedup vs baseline: 1.0395x; 1.0239x over previous
//
#include <hip/hip_runtime.h>
#include <stdint.h>

#define Bc 2
#define Tc 2048
#define Cn 1024
#define Hc 16
#define CAc 64

typedef __attribute__((ext_vector_type(8))) short short8;
typedef __attribute__((ext_vector_type(4))) float f32x4;

// 0.125 (1/sqrt(64)) * log2(e): folded into q so attention uses raw v_exp_f32.
#define QSCALE 0.18033688011112042f

__device__ __forceinline__ unsigned short f2bf(float f) {
    unsigned int u = __builtin_bit_cast(unsigned int, f);
    return (unsigned short)((u + 0x7fffu + ((u >> 16) & 1u)) >> 16);
}
__device__ __forceinline__ unsigned int pack_rne(float a, float b) {
    return (unsigned int)f2bf(a) | ((unsigned int)f2bf(b) << 16);
}
// truncating bf16x2 pack in ONE v_perm_b32 (bias cancels in the P/sum ratio)
__device__ __forceinline__ unsigned int pack_trunc(float a, float b) {
    return __builtin_amdgcn_perm(__builtin_bit_cast(unsigned int, b),
                                 __builtin_bit_cast(unsigned int, a), 0x07060302u);
}

// async global->LDS, 16B per lane; HW scatters lane i to lds_base + i*16
__device__ __forceinline__ void async_cp16(const unsigned short* g, unsigned short* l) {
    __builtin_amdgcn_global_load_lds(
        (const __attribute__((address_space(1))) unsigned int*)g,
        (__attribute__((address_space(3))) unsigned int*)l,
        16, 0, 0);
}

// Self-detect input dtype from x. 1 -> bf16, 0 -> f32. Uniform across blocks.
__device__ __forceinline__ int detect_bf16(const unsigned short* x) {
    int c = 0;
#pragma unroll
    for (int i = 0; i < 64; i++) {
        unsigned short u = x[i * 2];           // even indices: f32 mantissa halves
        int e = (u >> 7) & 0xFF;
        c += (e >= 0x68 && e <= 0x90);
    }
    return c > 32;
}

__device__ __forceinline__ unsigned short ld_elem(const void* base, size_t off, int isbf) {
    return isbf ? ((const unsigned short*)base)[off] : f2bf(((const float*)base)[off]);
}

// ---------------------------------------------------------------------------
// prep: blocks [0,4096): convert x -> xb (skipped when x is bf16).
// [4096,7168): transpose w_q/w_k/w_v. [7168,8192): transpose w_o.
// ---------------------------------------------------------------------------
__global__ __launch_bounds__(256) void prep(
    const void* __restrict__ xin, unsigned short* __restrict__ xb,
    const void* __restrict__ wq, const void* __restrict__ wk,
    const void* __restrict__ wv, const void* __restrict__ wo,
    unsigned short* __restrict__ wT, unsigned short* __restrict__ woT)
{
    const int isbf = detect_bf16((const unsigned short*)xin);
    const int bx = blockIdx.x;
    if (bx < 4096) {
        if (isbf) return;
        int idx = (bx * 256 + threadIdx.x) * 4;
        const float* xf = (const float*)xin;
        float4 v = *(const float4*)(xf + idx);
        uint2 p;
        p.x = pack_rne(v.x, v.y);
        p.y = pack_rne(v.z, v.w);
        *(uint2*)(&xb[idx]) = p;
        return;
    }
    __shared__ unsigned short tile[32][33];
    const int t = threadIdx.x;
    const int tx = t & 31, ty = t >> 5;
    const void* src;
    unsigned short* dst;
    int R, Cw, r0, c0;
    if (bx < 7168) {
        int rem0 = bx - 4096;
        int g = rem0 >> 6;            // proj*16 + h
        int rem = rem0 & 63;
        int ct = rem >> 1;
        int at = rem & 1;
        int proj = g >> 4, h = g & 15;
        const void* wsel = (proj == 0) ? wq : ((proj == 1) ? wk : wv);
        src = isbf ? (const void*)((const unsigned short*)wsel + (size_t)h * Cn * CAc)
                   : (const void*)((const float*)wsel + (size_t)h * Cn * CAc);
        dst = wT + (size_t)g * CAc * Cn;
        R = Cn; Cw = CAc; r0 = ct * 32; c0 = at * 32;
    } else {
        int rem = bx - 7168;
        src = wo; dst = woT;
        R = Cn; Cw = Cn;
        r0 = (rem >> 5) * 32; c0 = (rem & 31) * 32;
    }
#pragma unroll
    for (int j = 0; j < 4; j++)
        tile[ty + j * 8][tx] = ld_elem(src, (size_t)(r0 + ty + j * 8) * Cw + c0 + tx, isbf);
    __syncthreads();
#pragma unroll
    for (int j = 0; j < 4; j++)
        dst[(size_t)(c0 + ty + j * 8) * R + r0 + tx] = tile[tx][ty + j * 8];
}

// ---------------------------------------------------------------------------
// QKV GEMM 128x128 block, TWO waves (128 threads), wave tile 64x128:
// LDS bytes/MAC drops 1.33x vs 64x64 wave tiles. K=1024, BK=32, async dbuf.
// q scaled by QSCALE. vT epilogue via LDS transpose (coalesced 16B stores).
// ---------------------------------------------------------------------------
__global__ __launch_bounds__(128, 2) void gemm_qkv(
    const void* __restrict__ xin,
    const unsigned short* __restrict__ xb,
    const unsigned short* __restrict__ Bt,
    unsigned short* __restrict__ o0,
    unsigned short* __restrict__ o1,
    unsigned short* __restrict__ o2)
{
    __shared__ alignas(16) unsigned short SH[4][128 * 32];   // Al=SH[0..1], Bl=SH[2..3]
    const int tid = threadIdx.x;
    const int wave = tid >> 6, lane = tid & 63;
    const int l15 = lane & 15, quad = lane >> 4;
    const int mBase = blockIdx.y * 128, nBase = blockIdx.x * 128;
    const int mOff = wave * 64;                   // wave tile: m 64, n 128

    const int isbf = detect_bf16((const unsigned short*)xin);
    const unsigned short* Amat = isbf ? (const unsigned short*)xin : xb;

    const int srow = lane >> 2;                   // 16 rows x 4 chunks per inst
    const int sgc  = (lane & 3) ^ (srow & 3);     // swizzled global chunk
    const int sw = (quad ^ (l15 & 3)) * 8;        // swizzled frag chunk

    f32x4 acc[4][8];
#pragma unroll
    for (int i = 0; i < 4; i++)
#pragma unroll
        for (int j = 0; j < 8; j++)
            acc[i][j] = (f32x4){0.f, 0.f, 0.f, 0.f};

    // stage K-step 0: wave stages its own 64 rows of A and of B (4 insts each)
#pragma unroll
    for (int t = 0; t < 4; t++) {
        int rl = wave * 64 + t * 16;
        async_cp16(Amat + (size_t)(mBase + rl + srow) * Cn + sgc * 8, &SH[0][rl * 32]);
        async_cp16(Bt   + (size_t)(nBase + rl + srow) * Cn + sgc * 8, &SH[2][rl * 32]);
    }
    __syncthreads();

    for (int kk = 0; kk < 32; kk++) {
        const int cur = kk & 1;
        if (kk < 31) {
            const int k1 = (kk + 1) * 32;
#pragma unroll
            for (int t = 0; t < 4; t++) {
                int rl = wave * 64 + t * 16;
                async_cp16(Amat + (size_t)(mBase + rl + srow) * Cn + k1 + sgc * 8, &SH[1 - cur][rl * 32]);
                async_cp16(Bt   + (size_t)(nBase + rl + srow) * Cn + k1 + sgc * 8, &SH[3 - cur][rl * 32]);
            }
        }
        short8 af[4], bfr[8];
#pragma unroll
        for (int i = 0; i < 4; i++)
            af[i] = *(const short8*)(&SH[cur][(mOff + i * 16 + l15) * 32 + sw]);
#pragma unroll
        for (int j = 0; j < 8; j++)
            bfr[j] = *(const short8*)(&SH[2 + cur][(j * 16 + l15) * 32 + sw]);
#pragma unroll
        for (int i = 0; i < 4; i++)
#pragma unroll
            for (int j = 0; j < 8; j++)
                acc[i][j] = __builtin_amdgcn_mfma_f32_16x16x32_bf16(af[i], bfr[j], acc[i][j], 0, 0, 0);
        __syncthreads();
    }

    const int bb = mBase >> 11;
    if (nBase < 2048) {
        const float sc = (nBase < 1024) ? QSCALE : 1.0f;
        unsigned short* dst = (nBase < 1024) ? o0 : o1;
#pragma unroll
        for (int i = 0; i < 4; i++) {
            int m0 = mBase + mOff + i * 16 + quad * 4;
            int t0 = m0 & (Tc - 1);
#pragma unroll
            for (int j = 0; j < 8; j++) {
                int n = nBase + j * 16 + l15;
                int h = (n >> 6) & 15, a = n & 63;
                size_t base = ((size_t)(bb * Hc + h) * Tc + t0) * CAc + a;
#pragma unroll
                for (int r = 0; r < 4; r++)
                    dst[base + (size_t)r * CAc] = f2bf(acc[i][j][r] * sc);
            }
        }
    } else {
        // v -> vT via LDS transpose (SH dead after K-loop; 32KB = 128x128)
        unsigned short* Cl = &SH[0][0];
#pragma unroll
        for (int i = 0; i < 4; i++) {
            int c16 = wave * 8 + i * 2 + (quad >> 1);      // 16B chunk of m (0..15)
            int p = quad & 1;                               // 8B half
#pragma unroll
            for (int j = 0; j < 8; j++) {
                int nl = j * 16 + l15;
                int cs = c16 ^ (nl & 7);
                uint2 v8;
                v8.x = pack_rne(acc[i][j][0], acc[i][j][1]);
                v8.y = pack_rne(acc[i][j][2], acc[i][j][3]);
                *(uint2*)(&Cl[nl * 128 + cs * 8 + p * 4]) = v8;
            }
        }
        __syncthreads();
        const int tLoc = mBase & (Tc - 1);                  // batch-local t base
#pragma unroll
        for (int pp = 0; pp < 16; pp++) {
            int vr = pp * 8 + wave * 4 + (lane >> 4);       // 0..127 (= n-local)
            int cc = lane & 15;                              // 16B chunk of t
            int cs = cc ^ (vr & 7);
            uint4 val = *(const uint4*)(&Cl[vr * 128 + cs * 8]);
            int n = nBase + vr;
            int hh = (n >> 6) & 15, a = n & 63;
            *(uint4*)(&o2[((size_t)(bb * Hc + hh) * CAc + a) * Tc + tLoc + cc * 8]) = val;
        }
    }
}

// ---------------------------------------------------------------------------
// Output GEMM: 64x128 tiles (512 blocks -> 2/CU), K=1024, BK=32, async dbuf.
// ---------------------------------------------------------------------------
__global__ __launch_bounds__(256) void gemm_out(
    const unsigned short* __restrict__ Amat,
    const unsigned short* __restrict__ Bt,
    void* __restrict__ o0,
    const void* __restrict__ xin)
{
    __shared__ alignas(16) unsigned short Al[2][64 * 32];
    __shared__ alignas(16) unsigned short Bl[2][128 * 32];
    const int tid = threadIdx.x;
    const int wave = tid >> 6, lane = tid & 63;
    const int l15 = lane & 15, quad = lane >> 4;
    const int mBase = blockIdx.y * 64, nBase = blockIdx.x * 128;
    const int mOff = (wave & 1) * 32, nOff = (wave >> 1) * 64;

    const int isbf = detect_bf16((const unsigned short*)xin);

    const int srow = lane >> 2;
    const int sgc  = (lane & 3) ^ (srow & 3);
    const int sw = (quad ^ (l15 & 3)) * 8;

    f32x4 acc[2][4];
#pragma unroll
    for (int i = 0; i < 2; i++)
#pragma unroll
        for (int j = 0; j < 4; j++)
            acc[i][j] = (f32x4){0.f, 0.f, 0.f, 0.f};

    {
        int rlA = wave * 16;
        async_cp16(Amat + (size_t)(mBase + rlA + srow) * Cn + sgc * 8, &Al[0][rlA * 32]);
#pragma unroll
        for (int t = 0; t < 2; t++) {
            int rlB = wave * 32 + t * 16;
            async_cp16(Bt + (size_t)(nBase + rlB + srow) * Cn + sgc * 8, &Bl[0][rlB * 32]);
        }
    }
    __syncthreads();

    for (int kk = 0; kk < 32; kk++) {
        const int cur = kk & 1;
        if (kk < 31) {
            const int k1 = (kk + 1) * 32;
            int rlA = wave * 16;
            async_cp16(Amat + (size_t)(mBase + rlA + srow) * Cn + k1 + sgc * 8, &Al[1 - cur][rlA * 32]);
#pragma unroll
            for (int t = 0; t < 2; t++) {
                int rlB = wave * 32 + t * 16;
                async_cp16(Bt + (size_t)(nBase + rlB + srow) * Cn + k1 + sgc * 8, &Bl[1 - cur][rlB * 32]);
            }
        }
        short8 af[2], bfr[4];
#pragma unroll
        for (int i = 0; i < 2; i++)
            af[i] = *(const short8*)(&Al[cur][(mOff + i * 16 + l15) * 32 + sw]);
#pragma unroll
        for (int j = 0; j < 4; j++)
            bfr[j] = *(const short8*)(&Bl[cur][(nOff + j * 16 + l15) * 32 + sw]);
#pragma unroll
        for (int i = 0; i < 2; i++)
#pragma unroll
            for (int j = 0; j < 4; j++)
                acc[i][j] = __builtin_amdgcn_mfma_f32_16x16x32_bf16(af[i], bfr[j], acc[i][j], 0, 0, 0);
        __syncthreads();
    }

#pragma unroll
    for (int i = 0; i < 2; i++) {
        int m0 = mBase + mOff + i * 16 + quad * 4;
#pragma unroll
        for (int j = 0; j < 4; j++) {
            int n = nBase + nOff + j * 16 + l15;
            if (isbf) {
#pragma unroll
                for (int r = 0; r < 4; r++)
                    ((unsigned short*)o0)[(size_t)(m0 + r) * Cn + n] = f2bf(acc[i][j][r]);
            } else {
#pragma unroll
                for (int r = 0; r < 4; r++)
                    ((float*)o0)[(size_t)(m0 + r) * Cn + n] = acc[i][j][r];
            }
        }
    }
}

// ---------------------------------------------------------------------------
// Flash attention, causal — REVERTED to the verified baseline structure
// (LDS-staged K/V dbuf, one 64-row q-tile per block, grid 1024 = 4/CU,
// heavy-first).  R0-R3 k-slice rewrites measured 46 µs vs baseline <=43:
// occupancy/balance changes were proven irrelevant (R0 4/CU == R3 2/CU),
// so the staged-broadcast structure wins on this shape.  Single addition:
// T5 s_setprio(1) around the MFMA clusters (+4-7% on phase-diverse attn,
// learn_hip m191; NOT applied to the lockstep GEMMs, m190 null).
// LDS exactly 40960 B.  exp2 via __builtin_amdgcn_exp2f.  S^T trick;
// P packs via v_perm truncation; row-sums via ones-MFMA.
// ---------------------------------------------------------------------------
__global__ __launch_bounds__(256, 4) void attn_t(
    const unsigned short* __restrict__ q,
    const unsigned short* __restrict__ k,
    const unsigned short* __restrict__ vT,
    unsigned short* __restrict__ y)
{
    __shared__ alignas(16) unsigned short Kl[2][64 * 64];   // 16 KB
    __shared__ alignas(16) unsigned short Vl[2][64 * 64];   // 16 KB
    __shared__ alignas(16) unsigned short Pl[4][16 * 64];   // 8 KB  -> total 40960
    const int bx = blockIdx.x;
    const int qt = 31 - (bx >> 5);                // heavy tiles first
    const int bh = bx & 31;
    const int h = bh & 15, b = bh >> 4;
    const int tid = threadIdx.x;
    const int wave = tid >> 6, lane = tid & 63;
    const int l15 = lane & 15, quad = lane >> 4;
    const int m0w = qt * 64 + wave * 16;
    const size_t bhoff = (size_t)(b * Hc + h);
    const unsigned short* qh = q + bhoff * Tc * CAc;
    const unsigned short* kh = k + bhoff * Tc * CAc;
    const unsigned short* vh = vT + bhoff * CAc * Tc;

    const int srow = (lane >> 3);
    const int sgc  = (lane & 7) ^ srow;
    const int h7 = l15 & 7;
    const int sw0 = ((quad ^ h7) << 3);
    const int sw1 = (((4 + quad) ^ h7) << 3);
    const int pw_m = 2 * h7;

    short8 qf[2];
#pragma unroll
    for (int s = 0; s < 2; s++)
        qf[s] = *(const short8*)(&qh[(size_t)(m0w + l15) * CAc + s * 32 + quad * 8]);

    f32x4 oacc[4], osum;
#pragma unroll
    for (int j2 = 0; j2 < 4; j2++) oacc[j2] = (f32x4){0.f, 0.f, 0.f, 0.f};
    osum = (f32x4){0.f, 0.f, 0.f, 0.f};

    const unsigned short ONE = 0x3F80;
    short8 ones;
#pragma unroll
    for (int i = 0; i < 8; i++) ones[i] = (short)ONE;

    unsigned short* Pw = &Pl[wave][0];

#pragma unroll
    for (int t = 0; t < 2; t++) {
        int rl = wave * 16 + t * 8;
        async_cp16(kh + (size_t)(rl + srow) * CAc + sgc * 8, &Kl[0][rl * 64]);
        async_cp16(vh + (size_t)(rl + srow) * Tc  + sgc * 8, &Vl[0][rl * 64]);
    }
    __syncthreads();

    for (int kt = 0; kt <= qt; kt++) {
        const int k0 = kt * 64;
        const int cur = kt & 1;
        if (kt < qt) {
            const unsigned short* kg = kh + (size_t)(k0 + 64) * CAc;
            const unsigned short* vg = vh + (k0 + 64);
#pragma unroll
            for (int t = 0; t < 2; t++) {
                int rl = wave * 16 + t * 8;
                async_cp16(kg + (size_t)(rl + srow) * CAc + sgc * 8, &Kl[1 - cur][rl * 64]);
                async_cp16(vg + (size_t)(rl + srow) * Tc  + sgc * 8, &Vl[1 - cur][rl * 64]);
            }
        }
        const unsigned short* Kc = Kl[cur];
        const unsigned short* Vc = Vl[cur];

        float sv[4][4];
        __builtin_amdgcn_s_setprio(1);
#pragma unroll
        for (int j = 0; j < 4; j++) {
            short8 kf0 = *(const short8*)(&Kc[(j * 16 + l15) * 64 + sw0]);
            short8 kf1 = *(const short8*)(&Kc[(j * 16 + l15) * 64 + sw1]);
            f32x4 z = (f32x4){0.f, 0.f, 0.f, 0.f};
            z = __builtin_amdgcn_mfma_f32_16x16x32_bf16(kf0, qf[0], z, 0, 0, 0);
            z = __builtin_amdgcn_mfma_f32_16x16x32_bf16(kf1, qf[1], z, 0, 0, 0);
#pragma unroll
            for (int r = 0; r < 4; r++) sv[j][r] = z[r];
        }
        __builtin_amdgcn_s_setprio(0);

        if (kt == qt) {
            int tg = m0w + l15;
#pragma unroll
            for (int j = 0; j < 4; j++)
#pragma unroll
                for (int r = 0; r < 4; r++) {
                    int sg = k0 + j * 16 + quad * 4 + r;
                    sv[j][r] = (sg <= tg) ? __builtin_amdgcn_exp2f(sv[j][r]) : 0.f;
                }
        } else {
#pragma unroll
            for (int j = 0; j < 4; j++)
#pragma unroll
                for (int r = 0; r < 4; r++)
                    sv[j][r] = __builtin_amdgcn_exp2f(sv[j][r]);
        }

        short8 pa[2];
#pragma unroll
        for (int j = 0; j < 4; j++) {
            uint2 v;
            v.x = pack_trunc(sv[j][0], sv[j][1]);
            v.y = pack_trunc(sv[j][2], sv[j][3]);
            *(uint2*)(&Pw[l15 * 64 + ((j * 4 + quad) ^ pw_m) * 4]) = v;
        }
#pragma unroll
        for (int c = 0; c < 2; c++)
            pa[c] = *(const short8*)(&Pw[l15 * 64 + ((c * 4 + quad) ^ h7) * 8]);

        __builtin_amdgcn_s_setprio(1);
#pragma unroll
        for (int c = 0; c < 2; c++) {
#pragma unroll
            for (int j2 = 0; j2 < 4; j2++) {
                short8 vb = *(const short8*)(&Vc[(j2 * 16 + l15) * 64 + (c ? sw1 : sw0)]);
                oacc[j2] = __builtin_amdgcn_mfma_f32_16x16x32_bf16(pa[c], vb, oacc[j2], 0, 0, 0);
            }
            osum = __builtin_amdgcn_mfma_f32_16x16x32_bf16(pa[c], ones, osum, 0, 0, 0);
        }
        __builtin_amdgcn_s_setprio(0);
        __syncthreads();
    }

    float ri[4];
#pragma unroll
    for (int r = 0; r < 4; r++) ri[r] = 1.0f / osum[r];
#pragma unroll
    for (int j2 = 0; j2 < 4; j2++) {
#pragma unroll
        for (int r = 0; r < 4; r++) {
            int t = m0w + quad * 4 + r;
            y[((size_t)b * Tc + t) * Cn + h * CAc + j2 * 16 + l15] = f2bf(oacc[j2][r] * ri[r]);
        }
    }
}

// ---------------------------------------------------------------------------
extern "C" void kernel_launch(void* const* d_in, const int* in_sizes, int n_in,
                              void* d_out, int out_size, void* d_ws, size_t ws_size,
                              hipStream_t stream) {
    const void* x  = d_in[0];
    const void* wq = d_in[1];
    const void* wk = d_in[2];
    const void* wv = d_in[3];
    const void* wo = d_in[4];
    char* ws = (char*)d_ws;
    // ws layout (MB): wT@1(6) | woT@7(2) | xb@9(8) | q@17(8) | k@25(8) | vT@33(8) | y@41(8)
    unsigned short* wT  = (unsigned short*)(ws + ((size_t)1 << 20));
    unsigned short* woT = (unsigned short*)(ws + ((size_t)7 << 20));
    unsigned short* xb  = (unsigned short*)(ws + ((size_t)9 << 20));
    unsigned short* qb  = (unsigned short*)(ws + ((size_t)17 << 20));
    unsigned short* kb  = (unsigned short*)(ws + ((size_t)25 << 20));
    unsigned short* vTb = (unsigned short*)(ws + ((size_t)33 << 20));
    unsigned short* yb  = (unsigned short*)(ws + ((size_t)41 << 20));

    prep<<<dim3(8192), dim3(256), 0, stream>>>(x, xb, wq, wk, wv, wo, wT, woT);
    gemm_qkv<<<dim3(24, 32), dim3(128), 0, stream>>>(x, xb, wT, qb, kb, vTb);
    attn_t<<<dim3(1024), dim3(256), 0, stream>>>(qb, kb, vTb, yb);
    gemm_out<<<dim3(8, 64), dim3(256), 0, stream>>>(yb, woT, d_out, x);
}